// Round 2
// baseline (110.388 us; speedup 1.0000x reference)
//
#include <hip/hip_runtime.h>
#include <math.h>

#define TPB 256
#define EPSF 1e-15f

// Fused prep + O(n^2) pair kernel.
// Each thread owns column j. Block (bx,by) covers j in [bx*256, ...) and
// i in [by*span, by*span+span), staged through LDS in chunks of <=256.
// A_j = sum_i d_i * exp(-0.5*dr^2), B_j = sum_i L_i * Phi(dr), dr=(R_i-R_j)/h.
// Phi via A&S 7.1.25 3-term erf (|eps|<=2.5e-5), REUSING the same exp:
//   z=|dr|/sqrt2, t=1/(1+p*z), erf=1-(a1 t+a2 t^2+a3 t^3)e^{-z^2}, e^{-z^2}=exp(-dr^2/2)
__global__ __launch_bounds__(TPB, 8) void pair_kernel(
    const float* __restrict__ m_z, const float* __restrict__ y,
    const float* __restrict__ delta,
    float* __restrict__ PA, float* __restrict__ PB,
    float* __restrict__ out, float inv_h, int n, int span) {
    __shared__ float4 tile[256];
    const int tid = threadIdx.x;
    const int j = blockIdx.x * TPB + tid;

    // own column value (recomputed per block; cheap vs a separate kernel)
    const float Rj = (m_z[2 * j] + __logf(y[j])) * inv_h;
    if (j == 0 && blockIdx.y == 0) out[0] = 0.0f;  // harness poisons d_out; finalize atomics onto this

    float accA = 0.0f, accB = 0.0f;
    const int ibeg = blockIdx.y * span;
    const int iend = ibeg + span;
    for (int c = ibeg; c < iend; c += 256) {
        const int cnt = min(256, iend - c);
        if (tid < cnt) {
            const int i = c + tid;
            const float g1 = m_z[2 * i];
            const float g2 = m_z[2 * i + 1];
            tile[tid] = make_float4((g1 + __logf(y[i])) * inv_h, delta[i],
                                    __expf(g2 - g1), 0.0f);
        }
        __syncthreads();
#pragma unroll 8
        for (int k = 0; k < cnt; ++k) {
            const float4 v = tile[k];                 // broadcast LDS read, conflict-free
            const float dr = v.x - Rj;                // (R_i - R_j)/h
            const float q = dr * dr;
            const float e = __builtin_amdgcn_exp2f(-0.72134752044448170368f * q); // exp(-q/2)
            // t = 1/(1 + (p/sqrt2)*|dr|); abs is a free source modifier
            const float t = __builtin_amdgcn_rcpf(fmaf(0.3326783f, fabsf(dr), 1.0f));
            // u = 0.5*poly*e with pre-halved A&S coefficients (a3,a2,a1)/2
            const float u = t * fmaf(t, fmaf(t, 0.3739278f, -0.0479399f), 0.1740121f) * e;
            const float s = copysignf(0.5f, dr);      // v_bfi
            const float phi = fmaf(s, fmaf(-2.0f, u, 1.0f), 0.5f); // dr>=0: 1-u, else u
            accA = fmaf(v.y, e, accA);
            accB = fmaf(v.z, phi, accB);
        }
        __syncthreads();
    }
    // unique slot per (i-block, j): no atomics, no zero-init needed
    PA[(size_t)blockIdx.y * n + j] = accA;
    PB[(size_t)blockIdx.y * n + j] = accB;
}

// out = (1/n) * sum_j d_j * (R_j - g2_j - log(c1*A_j + eps) + log(B_j/n + eps))
__global__ void finalize_kernel(const float* __restrict__ PA, const float* __restrict__ PB,
                                const float* __restrict__ m_z, const float* __restrict__ y,
                                const float* __restrict__ delta, float* __restrict__ out,
                                float c1, float invn, int n, int ib) {
    const int j = blockIdx.x * TPB + threadIdx.x;
    float sa = 0.0f, sb = 0.0f;
    for (int b = 0; b < ib; ++b) {   // coalesced across threads for each b
        sa += PA[(size_t)b * n + j];
        sb += PB[(size_t)b * n + j];
    }
    const float d = delta[j];
    const float R = m_z[2 * j] + __logf(y[j]);
    float term = d * (R - m_z[2 * j + 1] - __logf(fmaf(c1, sa, EPSF))
                                         + __logf(fmaf(invn, sb, EPSF)));
    for (int o = 32; o > 0; o >>= 1) term += __shfl_down(term, o, 64);
    __shared__ float wsum[TPB / 64];
    if ((threadIdx.x & 63) == 0) wsum[threadIdx.x >> 6] = term;
    __syncthreads();
    if (threadIdx.x == 0) {
        float ssum = 0.0f;
        for (int w = 0; w < TPB / 64; ++w) ssum += wsum[w];
        atomicAdd(out, ssum * invn);
    }
}

extern "C" void kernel_launch(void* const* d_in, const int* in_sizes, int n_in,
                              void* d_out, int out_size, void* d_ws, size_t ws_size,
                              hipStream_t stream) {
    const float* m_z   = (const float*)d_in[0];   // (n,2)
    const float* y     = (const float*)d_in[1];   // (n,1)
    const float* delta = (const float*)d_in[2];   // (n,1)
    float* out = (float*)d_out;
    const int n = in_sizes[1];                    // 8192

    // Partial buffers PA/PB: IB rows of n floats each. Pick the largest IB
    // (<=64, pow2) that fits ws_size; IB=64 -> 2048 blocks = 8 blocks/CU.
    int IB = 64;
    while (IB > 1 && (size_t)IB * (size_t)n * 2u * sizeof(float) > ws_size) IB >>= 1;
    const int span = n / IB;

    float* PA = (float*)d_ws;
    float* PB = PA + (size_t)IB * n;

    const double h = 1.3 * pow((double)n, -0.2);
    const float inv_h = (float)(1.0 / h);
    const float c1 = (float)(0.3989422804014327 / ((double)n * h));  // INV_SQRT_2PI/(n*h)
    const float invn = 1.0f / (float)n;

    const int nblk = (n + TPB - 1) / TPB;  // 32
    dim3 grid(nblk, IB);
    pair_kernel<<<grid, TPB, 0, stream>>>(m_z, y, delta, PA, PB, out, inv_h, n, span);
    finalize_kernel<<<nblk, TPB, 0, stream>>>(PA, PB, m_z, y, delta, out, c1, invn, n, IB);
}

// Round 3
// 107.402 us; speedup vs baseline: 1.0278x; 1.0278x over previous
//
#include <hip/hip_runtime.h>
#include <math.h>

#define TPB 256
#define EPSF 1e-15f

// Setup: rdl[i] = {R_i/h, delta_i, L_i, 0}; per-block sum of L into SLpart;
// zero out[0] (harness poisons it 0xAA).
__global__ __launch_bounds__(TPB) void setup_kernel(
    const float* __restrict__ m_z, const float* __restrict__ y,
    const float* __restrict__ delta, float4* __restrict__ rdl,
    float* __restrict__ SLpart, float* __restrict__ out, float inv_h, int n) {
    const int i = blockIdx.x * TPB + threadIdx.x;
    float l = 0.0f;
    if (i < n) {
        const float g1 = m_z[2 * i];
        const float g2 = m_z[2 * i + 1];
        l = __expf(g2 - g1);
        rdl[i] = make_float4((g1 + __logf(y[i])) * inv_h, delta[i], l, 0.0f);
    }
    // block-reduce l -> SLpart[blockIdx.x]
    float s = l;
    for (int o = 32; o > 0; o >>= 1) s += __shfl_down(s, o, 64);
    __shared__ float wsum[TPB / 64];
    if ((threadIdx.x & 63) == 0) wsum[threadIdx.x >> 6] = s;
    __syncthreads();
    if (threadIdx.x == 0) {
        float b = 0.0f;
        for (int w = 0; w < TPB / 64; ++w) b += wsum[w];
        SLpart[blockIdx.x] = b;
    }
    if (i == 0) out[0] = 0.0f;
}

// O(n^2) pair kernel, scalar-broadcast inner loop (no LDS, no barriers).
// Thread owns column j; loop i over this block's span via wave-uniform
// rdl[i] reads (compiler -> s_load_dwordx4, scalar pipe).
//   accA = sum_i d_i * e_ij,                      e = exp(-0.5*dr^2)
//   accB = sum_i copysign(L_i, dr)*(0.5 - u_ij),  u = 0.5*(1-erf(|dr|/sqrt2))
// (B_j = 0.5*SL_total + sum_blocks accB, folded in finalize.)
// erf via A&S 7.1.25 3-term, REUSING the same exp (z^2 = dr^2/2).
__global__ __launch_bounds__(TPB, 8) void pair_kernel(
    const float4* __restrict__ rdl, float2* __restrict__ P, int n, int span) {
    const int j = blockIdx.x * TPB + threadIdx.x;
    const float Rj = rdl[j].x;  // pre-scaled R/h (divergent load, once)
    const float4* __restrict__ p = rdl + blockIdx.y * span;

    float accA = 0.0f, accB = 0.0f;
#pragma unroll 8
    for (int k = 0; k < span; ++k) {
        const float4 v = p[k];                    // uniform -> SGPR broadcast
        const float dr = v.x - Rj;                // (R_i - R_j)/h
        const float q = dr * dr;
        const float e = __builtin_amdgcn_exp2f(-0.72134752044448170368f * q); // exp(-q/2)
        const float t = __builtin_amdgcn_rcpf(fmaf(0.3326783f, fabsf(dr), 1.0f));
        // u = 0.5*(a1 t + a2 t^2 + a3 t^3) * e, pre-halved A&S coefficients
        const float u = t * fmaf(t, fmaf(t, 0.3739278f, -0.0479399f), 0.1740121f) * e;
        const float g = 0.5f - u;
        const float sl = copysignf(v.z, dr);      // L_i * sgn(dr), L_i > 0 (v_bfi)
        accA = fmaf(v.y, e, accA);
        accB = fmaf(sl, g, accB);
    }
    P[(size_t)blockIdx.y * n + j] = make_float2(accA, accB);
}

// out = (1/n) * sum_j d_j * (R_j - g2_j - log(c1*A_j + eps) + log(invn*B_j + eps))
__global__ __launch_bounds__(TPB) void finalize_kernel(
    const float2* __restrict__ P, const float* __restrict__ SLpart,
    const float* __restrict__ m_z, const float* __restrict__ y,
    const float* __restrict__ delta, float* __restrict__ out,
    float c1, float invn, int n, int ib, int nsl) {
    const int j = blockIdx.x * TPB + threadIdx.x;
    float slt = 0.0f;
    for (int b = 0; b < nsl; ++b) slt += SLpart[b];  // uniform -> scalar loads
    float sa = 0.0f, sb = 0.0f;
    for (int b = 0; b < ib; ++b) {                   // coalesced float2 reads
        const float2 v = P[(size_t)b * n + j];
        sa += v.x;
        sb += v.y;
    }
    sb += 0.5f * slt;                                // fold the 0.5*sum(L) term
    const float d = delta[j];
    const float R = m_z[2 * j] + __logf(y[j]);
    float term = d * (R - m_z[2 * j + 1] - __logf(fmaf(c1, sa, EPSF))
                                         + __logf(fmaf(invn, sb, EPSF)));
    for (int o = 32; o > 0; o >>= 1) term += __shfl_down(term, o, 64);
    __shared__ float wsum[TPB / 64];
    if ((threadIdx.x & 63) == 0) wsum[threadIdx.x >> 6] = term;
    __syncthreads();
    if (threadIdx.x == 0) {
        float ssum = 0.0f;
        for (int w = 0; w < TPB / 64; ++w) ssum += wsum[w];
        atomicAdd(out, ssum * invn);
    }
}

extern "C" void kernel_launch(void* const* d_in, const int* in_sizes, int n_in,
                              void* d_out, int out_size, void* d_ws, size_t ws_size,
                              hipStream_t stream) {
    const float* m_z   = (const float*)d_in[0];   // (n,2)
    const float* y     = (const float*)d_in[1];   // (n,1)
    const float* delta = (const float*)d_in[2];   // (n,1)
    float* out = (float*)d_out;
    const int n = in_sizes[1];                    // 8192

    const int nblk = (n + TPB - 1) / TPB;         // 32

    // ws layout: P (IB*n float2) | rdl (n float4) | SLpart (nblk floats)
    int IB = 64;                                  // 2048 blocks = 8 blocks/CU
    while (IB > 1 &&
           (size_t)IB * n * sizeof(float2) + (size_t)n * sizeof(float4) +
           (size_t)nblk * sizeof(float) > ws_size) IB >>= 1;
    const int span = n / IB;

    float2* P = (float2*)d_ws;
    float4* rdl = (float4*)((char*)d_ws + (size_t)IB * n * sizeof(float2));
    float* SLpart = (float*)((char*)rdl + (size_t)n * sizeof(float4));

    const double h = 1.3 * pow((double)n, -0.2);
    const float inv_h = (float)(1.0 / h);
    const float c1 = (float)(0.3989422804014327 / ((double)n * h));  // INV_SQRT_2PI/(n*h)
    const float invn = 1.0f / (float)n;

    setup_kernel<<<nblk, TPB, 0, stream>>>(m_z, y, delta, rdl, SLpart, out, inv_h, n);
    dim3 grid(nblk, IB);
    pair_kernel<<<grid, TPB, 0, stream>>>(rdl, P, n, span);
    finalize_kernel<<<nblk, TPB, 0, stream>>>(P, SLpart, m_z, y, delta, out,
                                              c1, invn, n, IB, nblk);
}

// Round 4
// 82.637 us; speedup vs baseline: 1.3358x; 1.2997x over previous
//
#include <hip/hip_runtime.h>
#include <math.h>

#define TPB 256
#define IB 64
#define EPSF 1e-15f

// Fused prep + O(n^2) pair kernel.
// Rs = (g1+log y)/(h*sqrt(2 ln 2)) so exp(-0.5*((R_i-R_j)/h)^2) = exp2(-dr^2).
// A_j = sum_i d_i*e;  L*Phi = 0.5*L + copysign(L,dr)*(0.5-u),
// u = upper-tail Q(|dr_true|) via A&S 7.1.25 3-term erfc (|eps|<=2.5e-5),
// reusing the SAME exp2. The 0.5*sum(L) over this block's span is folded in
// once (spans partition i, so the block sum telescopes to 0.5*sum_all L).
__global__ __launch_bounds__(TPB, 8) void pair_kernel(
    const float* __restrict__ m_z, const float* __restrict__ y,
    const float* __restrict__ delta, float2* __restrict__ P,
    float* __restrict__ out, float inv_hk, int n, int span) {
    __shared__ float4 sRd[128];   // {R_2k, R_2k+1, d_2k, d_2k+1}
    __shared__ float2 sL2[128];   // {L_2k, L_2k+1}
    __shared__ float sLtot;
    const int tid = threadIdx.x;
    const int j = blockIdx.x * TPB + tid;
    const float2* __restrict__ mz2 = (const float2*)m_z;

    const float2 gj = mz2[j];
    const float Rj = (gj.x + __logf(y[j])) * inv_hk;

    // prep this block's i-span into LDS (span <= 256)
    const int ibase = blockIdx.y * span;
    if (tid < span) {
        const int i = ibase + tid;
        const float2 g = mz2[i];
        float* s = (float*)sRd;
        const int pk = tid >> 1, hf = tid & 1;
        s[4 * pk + hf]     = (g.x + __logf(y[i])) * inv_hk;
        s[4 * pk + 2 + hf] = delta[i];
        ((float*)sL2)[tid] = __expf(g.y - g.x);
    }
    __syncthreads();
    if (tid < 64) {  // wave 0: sum L over the span
        float s = 0.0f;
        for (int t = tid; t < span; t += 64) s += ((float*)sL2)[t];
        for (int o = 32; o > 0; o >>= 1) s += __shfl_down(s, o, 64);
        if (tid == 0) sLtot = s;
    }
    __syncthreads();
    if (j == 0 && blockIdx.y == 0) out[0] = 0.0f;  // harness poisons d_out

    float a0 = 0.0f, a1 = 0.0f, b0 = 0.5f * sLtot, b1 = 0.0f;
    const int m = span >> 1;
#pragma unroll 4
    for (int k = 0; k < m; ++k) {
        const float4 rd = sRd[k];                 // broadcast LDS reads
        const float2 ll = sL2[k];
        const float dr0 = rd.x - Rj;
        const float dr1 = rd.y - Rj;
        const float e0 = __builtin_amdgcn_exp2f(-(dr0 * dr0));  // exp(-drt^2/2)
        const float e1 = __builtin_amdgcn_exp2f(-(dr1 * dr1));
        const float t0 = __builtin_amdgcn_rcpf(fmaf(0.3916993f, fabsf(dr0), 1.0f));
        const float t1 = __builtin_amdgcn_rcpf(fmaf(0.3916993f, fabsf(dr1), 1.0f));
        const float u0 = t0 * fmaf(t0, fmaf(t0, 0.3739278f, -0.0479399f), 0.1740121f) * e0;
        const float u1 = t1 * fmaf(t1, fmaf(t1, 0.3739278f, -0.0479399f), 0.1740121f) * e1;
        a0 = fmaf(rd.z, e0, a0);
        a1 = fmaf(rd.w, e1, a1);
        b0 = fmaf(copysignf(ll.x, dr0), 0.5f - u0, b0);
        b1 = fmaf(copysignf(ll.y, dr1), 0.5f - u1, b1);
    }
    P[(size_t)blockIdx.y * n + j] = make_float2(a0 + a1, b0 + b1);
}

// out = (1/n) * sum_j d_j * (R_j - g2_j - log(c1*A_j + eps) + log(invn*B_j + eps))
__global__ __launch_bounds__(TPB) void finalize_kernel(
    const float2* __restrict__ P, const float* __restrict__ m_z,
    const float* __restrict__ y, const float* __restrict__ delta,
    float* __restrict__ out, float c1, float invn, int n) {
    const int j = blockIdx.x * TPB + threadIdx.x;
    float sa = 0.0f, sb = 0.0f;
    for (int b = 0; b < IB; ++b) {               // coalesced float2 reads
        const float2 v = P[(size_t)b * n + j];
        sa += v.x;
        sb += v.y;
    }
    const float d = delta[j];
    const float R = m_z[2 * j] + __logf(y[j]);
    float term = d * (R - m_z[2 * j + 1] - __logf(fmaf(c1, sa, EPSF))
                                         + __logf(fmaf(invn, sb, EPSF)));
    for (int o = 32; o > 0; o >>= 1) term += __shfl_down(term, o, 64);
    __shared__ float wsum[TPB / 64];
    if ((threadIdx.x & 63) == 0) wsum[threadIdx.x >> 6] = term;
    __syncthreads();
    if (threadIdx.x == 0) {
        float ssum = 0.0f;
        for (int w = 0; w < TPB / 64; ++w) ssum += wsum[w];
        atomicAdd(out, ssum * invn);
    }
}

extern "C" void kernel_launch(void* const* d_in, const int* in_sizes, int n_in,
                              void* d_out, int out_size, void* d_ws, size_t ws_size,
                              hipStream_t stream) {
    const float* m_z   = (const float*)d_in[0];   // (n,2)
    const float* y     = (const float*)d_in[1];   // (n,1)
    const float* delta = (const float*)d_in[2];   // (n,1)
    float* out = (float*)d_out;
    const int n = in_sizes[1];                    // 8192

    float2* P = (float2*)d_ws;                    // IB * n * 8 B = 4 MB

    const double h = 1.3 * pow((double)n, -0.2);
    const double k = 1.1774100225154747;          // sqrt(2 ln 2)
    const float inv_hk = (float)(1.0 / (h * k));
    const float c1 = (float)(0.3989422804014327 / ((double)n * h)); // INV_SQRT_2PI/(n*h)
    const float invn = 1.0f / (float)n;
    const int span = n / IB;                      // 128

    const int nblk = (n + TPB - 1) / TPB;         // 32
    dim3 grid(nblk, IB);                          // 2048 blocks = 8/CU
    pair_kernel<<<grid, TPB, 0, stream>>>(m_z, y, delta, P, out, inv_hk, n, span);
    finalize_kernel<<<nblk, TPB, 0, stream>>>(P, m_z, y, delta, out, c1, invn, n);
}